// Round 3
// baseline (366.355 us; speedup 1.0000x reference)
//
#include <hip/hip_runtime.h>
#include <math.h>

typedef __bf16 bf16_t;
typedef bf16_t bf16x8 __attribute__((ext_vector_type(8)));
typedef float  floatx4 __attribute__((ext_vector_type(4)));

#define MFMA16(a, b, c) __builtin_amdgcn_mfma_f32_16x16x32_bf16((a), (b), (c), 0, 0, 0)

// Problem constants
constexpr int NTOT = 256 * 512;   // 131072 samples
constexpr int CDIM = 256;         // K for all GEMMs

// ws: flat stream of 88 weight tiles in USE ORDER; tile = 16 output cols x 256 k
// in MFMA B-fragment order: tile[ks][lane][j] (8 KB). Wave B-load = contiguous 1 KB.
//   tiles  0..15 : w1a   (phase A,  groups  0..7)
//   tiles 16..19 : wb1   (phase B1, groups  8..9)
//   tiles 20..51 : w1b   (phase B2, groups 10..25)
//   tiles 52..67 : w2a   (phase C,  groups 26..33)
//   tiles 68..71 : w2b   (phase D,  groups 34..35)
//   tiles 72..87 : wb2a  (phase E,  groups 36..43)
constexpr int N_TILES  = 88;
constexpr int WS_ELEMS = N_TILES * 4096;

// ---------------------------------------------------------------------------
__global__ void prep_weights(const float* __restrict__ w1a, const float* __restrict__ w1b,
                             const float* __restrict__ w2a, const float* __restrict__ w2b,
                             const float* __restrict__ wb1, const float* __restrict__ wb2a,
                             bf16_t* __restrict__ ws) {
  int idx = blockIdx.x * 256 + threadIdx.x;
  if (idx >= WS_ELEMS) return;
  int t   = idx >> 12;       // tile
  int rel = idx & 4095;
  const float* src; int dout; int ct;
  if      (t < 16) { src = w1a;  dout = 256; ct = t; }
  else if (t < 20) { src = wb1;  dout = 64;  ct = t - 16; }
  else if (t < 52) { src = w1b;  dout = 512; ct = t - 20; }
  else if (t < 68) { src = w2a;  dout = 256; ct = t - 52; }
  else if (t < 72) { src = w2b;  dout = 64;  ct = t - 68; }
  else             { src = wb2a; dout = 256; ct = t - 72; }
  int j    = rel & 7;
  int lane = (rel >> 3) & 63;
  int ks   = rel >> 9;
  int o = ct * 16 + (lane & 15);
  int k = ks * 32 + (lane >> 4) * 8 + j;
  ws[idx] = (bf16_t)src[(size_t)k * dout + o];
}

// ---------------------------------------------------------------------------
// BARRIER-FREE STREAMING VERSION (R2 post-mortem).
//
// Residency analysis: sA(64) + hA(64) + hid(32) + transients ≈ 190 regs/wave
// (CSV VGPR_Count=112 excludes the AGPR side of the unified file) -> hard
// 2 waves/SIMD ceiling. R1 vs R2 proved it: VGPR 64 -> 2 blocks resident,
// VGPR 112 -> 1 block, LDS/threads identical. More TLP is unreachable
// without dropping sA or hA (both structurally required).
//
// So attack latency with ILP: the weight stream is only 704 KB, fully
// L1/L2-resident (every wave reads the same bytes near-lockstep). Drop the
// block-shared LDS wbuf + stage() + all 44 __syncthreads() (each forced a
// vmcnt(0) drain and 8-wave rendezvous ~4300 cyc/group) and read B-fragments
// DIRECTLY from global into registers: 8 outstanding global_load_dwordx4 per
// gemm, no barrier anywhere, compiler free to pipeline loads across groups.
// LDS keeps only the per-wave t_s transpose bounce + q_s (13 KB) — wave-
// internal LDS ordering needs no barrier.
//
// Block = 4 waves = 128 rows (no block-shared state left), grid = 1024.
// __launch_bounds__(256,2) -> reg cap 256: room for load pipelining, no spill.
//
// CRITICAL (R3-R5 post-mortem): every register array (sA, hA, hid, pj, pb, b)
// must be indexed ONLY with compile-time constants, else LLVM demotes it to
// scratch (observed as 131-256 MB WRITE_SIZE). Hence full unrolling below.
// ---------------------------------------------------------------------------
__global__ __launch_bounds__(256, 2)
void mixing_fused(const float* __restrict__ q,     // [N,8]
                  const float* __restrict__ st,    // [N,256]
                  const bf16_t* __restrict__ W,    // ws (tile stream)
                  const float* __restrict__ b1a, const float* __restrict__ b1b,
                  const float* __restrict__ b2a, const float* __restrict__ b2b,
                  const float* __restrict__ bb1,
                  const float* __restrict__ bb2a,
                  const float* __restrict__ wb2b, const float* __restrict__ bb2b,
                  float* __restrict__ out) {
  __shared__ __align__(16) bf16_t t_s[4][32][36]; // per-wave bounce (transpose)
  __shared__ __align__(16) float  q_s[4][256];    // per-wave q staging

  const int tid  = threadIdx.x;
  const int wid  = tid >> 6;      // 0..3
  const int lane = tid & 63;
  const int l15  = lane & 15;
  const int quad = lane >> 4;
  const int m0   = blockIdx.x * 128 + wid * 32;

  // ---- wave-local q staging ----
  *(float4*)&q_s[wid][lane * 4] = *(const float4*)(q + (size_t)m0 * 8 + lane * 4);

  // ---- st A-fragments straight from global (coalesced), cvt to bf16 ----
  bf16x8 sA[2][8];
#pragma unroll
  for (int rt = 0; rt < 2; ++rt) {
    const float* rp = st + (size_t)(m0 + rt * 16 + l15) * CDIM;
#pragma unroll
    for (int ks = 0; ks < 8; ++ks) {
      int k0 = ks * 32 + quad * 8;
      float4 f0 = *(const float4*)(rp + k0);
      float4 f1 = *(const float4*)(rp + k0 + 4);
      bf16x8 v;
      v[0] = (bf16_t)f0.x; v[1] = (bf16_t)f0.y; v[2] = (bf16_t)f0.z; v[3] = (bf16_t)f0.w;
      v[4] = (bf16_t)f1.x; v[5] = (bf16_t)f1.y; v[6] = (bf16_t)f1.z; v[7] = (bf16_t)f1.w;
      sA[rt][ks] = v;
    }
  }

  // GEMM: 16-col tile h (0/1) of weight group g, B-fragments streamed from
  // global (L1/L2-resident, 8 outstanding dwordx4), both row tiles.
  auto gemmG = [&](int g, int h, const bf16x8 (&A)[2][8], floatx4 (&acc)[2]) {
    const bf16_t* wp = W + (size_t)g * 8192 + h * 4096 + lane * 8;
    bf16x8 b[8];
#pragma unroll
    for (int kk = 0; kk < 8; ++kk)
      b[kk] = *(const bf16x8*)(wp + kk * 512);
    floatx4 z = {0.f, 0.f, 0.f, 0.f};
    acc[0] = z; acc[1] = z;
#pragma unroll
    for (int kk = 0; kk < 8; ++kk) {
      acc[0] = MFMA16(A[0][kk], b[kk], acc[0]);
      acc[1] = MFMA16(A[1][kk], b[kk], acc[1]);
    }
  };

  bf16x8 hA[2][8];

  // ========= Phase A: H1 = elu(st @ w1a + b1a)   groups 0..7 (FULL unroll) ===
#pragma unroll
  for (int ks = 0; ks < 8; ++ks) {
#pragma unroll
    for (int h = 0; h < 2; ++h) {
      int ct = 2 * ks + h;
      floatx4 acc[2];
      gemmG(ks, h, sA, acc);
      float bias = b1a[ct * 16 + l15];
#pragma unroll
      for (int rt = 0; rt < 2; ++rt)
#pragma unroll
        for (int i = 0; i < 4; ++i) {
          float v = acc[rt][i] + bias;
          v = v > 0.f ? v : (__expf(v) - 1.f);
          t_s[wid][rt * 16 + quad * 4 + i][h * 16 + l15] = (bf16_t)v;
        }
    }
#pragma unroll
    for (int rt = 0; rt < 2; ++rt)
      hA[rt][ks] = *(const bf16x8*)&t_s[wid][rt * 16 + l15][quad * 8];
  }

  // ========= Phase B1: hidden = st @ wb1 + bb1   groups 8..9 (FULL unroll) ===
  floatx4 hid[2][4];
#pragma unroll
  for (int gg = 0; gg < 2; ++gg) {
#pragma unroll
    for (int h = 0; h < 2; ++h) {
      int et = 2 * gg + h;
      floatx4 acc[2];
      gemmG(8 + gg, h, sA, acc);
      float bias = bb1[et * 16 + l15];
      hid[0][et] = acc[0] + bias;
      hid[1][et] = acc[1] + bias;
    }
  }

  // ==== Phase B2: W1 = |H1 @ w1b + b1b|; hidden += q.*W1   groups 10..25 =====
  // outer a runtime, inner fully unrolled so et (hid index) is constant.
#pragma unroll 1
  for (int a = 0; a < 8; ++a) {
#pragma unroll
    for (int g2 = 0; g2 < 2; ++g2) {
      const int idx = a * 2 + g2;          // 0..15
#pragma unroll
      for (int h = 0; h < 2; ++h) {
        int ct = a * 4 + g2 * 2 + h;
        const int et = g2 * 2 + h;         // constant
        floatx4 acc[2];
        gemmG(10 + idx, h, hA, acc);
        float bias = b1b[ct * 16 + l15];
#pragma unroll
        for (int rt = 0; rt < 2; ++rt)
#pragma unroll
          for (int i = 0; i < 4; ++i) {
            float w1v = fabsf(acc[rt][i] + bias);
            float qv  = q_s[wid][(rt * 16 + quad * 4 + i) * 8 + a];
            hid[rt][et][i] += qv * w1v;
          }
      }
    }
  }
  // relu
#pragma unroll
  for (int rt = 0; rt < 2; ++rt)
#pragma unroll
    for (int et = 0; et < 4; ++et)
#pragma unroll
      for (int i = 0; i < 4; ++i) hid[rt][et][i] = fmaxf(hid[rt][et][i], 0.f);

  // ========= Phase C: H2 = elu(st @ w2a + b2a)  groups 26..33 (FULL unroll) ==
#pragma unroll
  for (int ks = 0; ks < 8; ++ks) {
#pragma unroll
    for (int h = 0; h < 2; ++h) {
      int ct = 2 * ks + h;
      floatx4 acc[2];
      gemmG(26 + ks, h, sA, acc);
      float bias = b2a[ct * 16 + l15];
#pragma unroll
      for (int rt = 0; rt < 2; ++rt)
#pragma unroll
        for (int i = 0; i < 4; ++i) {
          float v = acc[rt][i] + bias;
          v = v > 0.f ? v : (__expf(v) - 1.f);
          t_s[wid][rt * 16 + quad * 4 + i][h * 16 + l15] = (bf16_t)v;
        }
    }
#pragma unroll
    for (int rt = 0; rt < 2; ++rt)
      hA[rt][ks] = *(const bf16x8*)&t_s[wid][rt * 16 + l15][quad * 8];
  }

  // ==== Phase D: W2 = |H2 @ w2b + b2b|; pj += hidden*W2   groups 34..35 ======
  float pj[2][4] = {{0.f, 0.f, 0.f, 0.f}, {0.f, 0.f, 0.f, 0.f}};
#pragma unroll
  for (int gg = 0; gg < 2; ++gg) {
#pragma unroll
    for (int h = 0; h < 2; ++h) {
      int et = 2 * gg + h;
      floatx4 acc[2];
      gemmG(34 + gg, h, hA, acc);
      float bias = b2b[et * 16 + l15];
#pragma unroll
      for (int rt = 0; rt < 2; ++rt)
#pragma unroll
        for (int i = 0; i < 4; ++i) {
          float w2v = fabsf(acc[rt][i] + bias);
          pj[rt][i] += hid[rt][et][i] * w2v;
        }
    }
  }

  // == Phase E: HB = elu(st @ wb2a + bb2a); pb += HB*wb2b   groups 36..43 =====
  float pb[2][4] = {{0.f, 0.f, 0.f, 0.f}, {0.f, 0.f, 0.f, 0.f}};
#pragma unroll 1
  for (int gg = 0; gg < 8; ++gg) {
#pragma unroll
    for (int h = 0; h < 2; ++h) {
      int ct = 2 * gg + h;
      floatx4 acc[2];
      gemmG(36 + gg, h, sA, acc);
      float bias = bb2a[ct * 16 + l15];
      float wv   = wb2b[ct * 16 + l15];
#pragma unroll
      for (int rt = 0; rt < 2; ++rt)
#pragma unroll
        for (int i = 0; i < 4; ++i) {
          float v = acc[rt][i] + bias;
          v = v > 0.f ? v : (__expf(v) - 1.f);
          pb[rt][i] += v * wv;
        }
    }
  }

  // ======= Reduce over 16 column lanes (same row), store joint output ========
  float bb2 = bb2b[0];
#pragma unroll
  for (int rt = 0; rt < 2; ++rt)
#pragma unroll
    for (int i = 0; i < 4; ++i) {
      float v = pj[rt][i] + pb[rt][i];
      v += __shfl_xor(v, 1);
      v += __shfl_xor(v, 2);
      v += __shfl_xor(v, 4);
      v += __shfl_xor(v, 8);
      if (l15 == 0) out[m0 + rt * 16 + quad * 4 + i] = v + bb2;
    }
}

// ---------------------------------------------------------------------------
extern "C" void kernel_launch(void* const* d_in, const int* in_sizes, int n_in,
                              void* d_out, int out_size, void* d_ws, size_t ws_size,
                              hipStream_t stream) {
  const float* q    = (const float*)d_in[0];
  const float* st   = (const float*)d_in[1];
  const float* w1a  = (const float*)d_in[2];
  const float* b1a  = (const float*)d_in[3];
  const float* w1b  = (const float*)d_in[4];
  const float* b1b  = (const float*)d_in[5];
  const float* w2a  = (const float*)d_in[6];
  const float* b2a  = (const float*)d_in[7];
  const float* w2b  = (const float*)d_in[8];
  const float* b2b  = (const float*)d_in[9];
  const float* wb1  = (const float*)d_in[10];
  const float* bb1  = (const float*)d_in[11];
  const float* wb2a = (const float*)d_in[12];
  const float* bb2a = (const float*)d_in[13];
  const float* wb2b = (const float*)d_in[14];
  const float* bb2b = (const float*)d_in[15];
  bf16_t* W = (bf16_t*)d_ws;

  hipLaunchKernelGGL(prep_weights, dim3((WS_ELEMS + 255) / 256), dim3(256), 0, stream,
                     w1a, w1b, w2a, w2b, wb1, wb2a, W);
  hipLaunchKernelGGL(mixing_fused, dim3(NTOT / 128), dim3(256), 0, stream,
                     q, st, W, b1a, b1b, b2a, b2b, bb1, bb2a, wb2b, bb2b, (float*)d_out);
}

// Round 4
// 356.928 us; speedup vs baseline: 1.0264x; 1.0264x over previous
//
#include <hip/hip_runtime.h>
#include <math.h>

typedef __bf16 bf16_t;
typedef bf16_t bf16x8 __attribute__((ext_vector_type(8)));
typedef float  floatx4 __attribute__((ext_vector_type(4)));

#define MFMA16(a, b, c) __builtin_amdgcn_mfma_f32_16x16x32_bf16((a), (b), (c), 0, 0, 0)

// Problem constants
constexpr int NTOT = 256 * 512;   // 131072 samples
constexpr int CDIM = 256;         // K for all GEMMs

// ws: flat stream of 88 weight tiles in USE ORDER; tile = 16 output cols x 256 k
// in MFMA B-fragment order: tile[ks][lane][j] (8 KB). Wave B-load = contiguous 1 KB.
//   tiles  0..15 : w1a   (phase A,  groups  0..7)
//   tiles 16..19 : wb1   (phase B1, groups  8..9)
//   tiles 20..51 : w1b   (phase B2, groups 10..25)
//   tiles 52..67 : w2a   (phase C,  groups 26..33)
//   tiles 68..71 : w2b   (phase D,  groups 34..35)
//   tiles 72..87 : wb2a  (phase E,  groups 36..43)
constexpr int N_TILES  = 88;
constexpr int WS_ELEMS = N_TILES * 4096;

// ---------------------------------------------------------------------------
__global__ void prep_weights(const float* __restrict__ w1a, const float* __restrict__ w1b,
                             const float* __restrict__ w2a, const float* __restrict__ w2b,
                             const float* __restrict__ wb1, const float* __restrict__ wb2a,
                             bf16_t* __restrict__ ws) {
  int idx = blockIdx.x * 256 + threadIdx.x;
  if (idx >= WS_ELEMS) return;
  int t   = idx >> 12;       // tile
  int rel = idx & 4095;
  const float* src; int dout; int ct;
  if      (t < 16) { src = w1a;  dout = 256; ct = t; }
  else if (t < 20) { src = wb1;  dout = 64;  ct = t - 16; }
  else if (t < 52) { src = w1b;  dout = 512; ct = t - 20; }
  else if (t < 68) { src = w2a;  dout = 256; ct = t - 52; }
  else if (t < 72) { src = w2b;  dout = 64;  ct = t - 68; }
  else             { src = wb2a; dout = 256; ct = t - 72; }
  int j    = rel & 7;
  int lane = (rel >> 3) & 63;
  int ks   = rel >> 9;
  int o = ct * 16 + (lane & 15);
  int k = ks * 32 + (lane >> 4) * 8 + j;
  ws[idx] = (bf16_t)src[(size_t)k * dout + o];
}

// ---------------------------------------------------------------------------
// DEPTH-1 SOFTWARE-PIPELINED STREAMING VERSION (R3 post-mortem).
//
// R3 measured ~2.8K cyc per 8KB weight tile vs ~300 cyc MFMA work + ~225 cyc
// L2 latency: the wave ran fully serial (loads -> waitcnt -> MFMA -> bias ->
// epilogue), and at 2 waves/SIMD (register-pinned: unified VGPR+AGPR state
// ~190-250) nothing hides it. The 88-tile weight stream is perfectly linear,
// so pipeline it explicitly: two statically-named B buffers; while tile t's
// 16 MFMAs consume B[t&1], issue tile t+1's 8 loads into B[~t&1]; load the
// epilogue bias BEFORE the MFMA block so its latency is covered too.
// Every phase handles an even number of tiles -> buffer parity is a
// compile-time constant everywhere, including across the #pragma unroll 1
// backedges of B2/E (runtime ADDRESSES are fine; only register-array INDICES
// must be static per the R3-R5 scratch-demotion rule).
//
// Block = 4 waves = 128 rows, grid = 1024 (2 clean residency rounds).
// __launch_bounds__(256,2) -> 256-reg cap; peak live ~245 (sA64 + hA64 +
// B0/B1 64 + hid32 + misc). WRITE_SIZE ballooning past ~10 MB = spill abort.
// ---------------------------------------------------------------------------
__global__ __launch_bounds__(256, 2)
void mixing_fused(const float* __restrict__ q,     // [N,8]
                  const float* __restrict__ st,    // [N,256]
                  const bf16_t* __restrict__ W,    // ws (tile stream)
                  const float* __restrict__ b1a, const float* __restrict__ b1b,
                  const float* __restrict__ b2a, const float* __restrict__ b2b,
                  const float* __restrict__ bb1,
                  const float* __restrict__ bb2a,
                  const float* __restrict__ wb2b, const float* __restrict__ bb2b,
                  float* __restrict__ out) {
  __shared__ __align__(16) bf16_t t_s[4][32][36]; // per-wave bounce (transpose)
  __shared__ __align__(16) float  q_s[4][256];    // per-wave q staging

  const int tid  = threadIdx.x;
  const int wid  = tid >> 6;      // 0..3
  const int lane = tid & 63;
  const int l15  = lane & 15;
  const int quad = lane >> 4;
  const int m0   = blockIdx.x * 128 + wid * 32;

  // ---- wave-local q staging ----
  *(float4*)&q_s[wid][lane * 4] = *(const float4*)(q + (size_t)m0 * 8 + lane * 4);

  // ---- st A-fragments straight from global (coalesced), cvt to bf16 ----
  bf16x8 sA[2][8];
#pragma unroll
  for (int rt = 0; rt < 2; ++rt) {
    const float* rp = st + (size_t)(m0 + rt * 16 + l15) * CDIM;
#pragma unroll
    for (int ks = 0; ks < 8; ++ks) {
      int k0 = ks * 32 + quad * 8;
      float4 f0 = *(const float4*)(rp + k0);
      float4 f1 = *(const float4*)(rp + k0 + 4);
      bf16x8 v;
      v[0] = (bf16_t)f0.x; v[1] = (bf16_t)f0.y; v[2] = (bf16_t)f0.z; v[3] = (bf16_t)f0.w;
      v[4] = (bf16_t)f1.x; v[5] = (bf16_t)f1.y; v[6] = (bf16_t)f1.z; v[7] = (bf16_t)f1.w;
      sA[rt][ks] = v;
    }
  }

  // issue 8 global_load_dwordx4 for tile (g,h) into buffer b
  auto LD = [&](bf16x8 (&b)[8], int g, int h) {
    const bf16_t* wp = W + (size_t)g * 8192 + h * 4096 + lane * 8;
#pragma unroll
    for (int kk = 0; kk < 8; ++kk)
      b[kk] = *(const bf16x8*)(wp + kk * 512);
  };
  // 16 MFMAs consuming buffer b against A fragments
  auto GEMM = [&](const bf16x8 (&A)[2][8], const bf16x8 (&b)[8], floatx4 (&acc)[2]) {
    floatx4 z = {0.f, 0.f, 0.f, 0.f};
    acc[0] = z; acc[1] = z;
#pragma unroll
    for (int kk = 0; kk < 8; ++kk) {
      acc[0] = MFMA16(A[0][kk], b[kk], acc[0]);
      acc[1] = MFMA16(A[1][kk], b[kk], acc[1]);
    }
  };

  bf16x8 B0[8], B1[8];
  LD(B0, 0, 0);                       // prologue: first tile in flight

  bf16x8 hA[2][8];

  // ========= Phase A: H1 = elu(st @ w1a + b1a)   groups 0..7 (FULL unroll) ===
#pragma unroll
  for (int ks = 0; ks < 8; ++ks) {
    // tile (ks,0) is in B0; prefetch (ks,1)
    LD(B1, ks, 1);
    {
      float bias = b1a[(2 * ks) * 16 + l15];
      floatx4 acc[2];
      GEMM(sA, B0, acc);
#pragma unroll
      for (int rt = 0; rt < 2; ++rt)
#pragma unroll
        for (int i = 0; i < 4; ++i) {
          float v = acc[rt][i] + bias;
          v = v > 0.f ? v : (__expf(v) - 1.f);
          t_s[wid][rt * 16 + quad * 4 + i][l15] = (bf16_t)v;
        }
    }
    // tile (ks,1) is in B1; prefetch next
    LD(B0, (ks < 7) ? ks + 1 : 8, 0);
    {
      float bias = b1a[(2 * ks + 1) * 16 + l15];
      floatx4 acc[2];
      GEMM(sA, B1, acc);
#pragma unroll
      for (int rt = 0; rt < 2; ++rt)
#pragma unroll
        for (int i = 0; i < 4; ++i) {
          float v = acc[rt][i] + bias;
          v = v > 0.f ? v : (__expf(v) - 1.f);
          t_s[wid][rt * 16 + quad * 4 + i][16 + l15] = (bf16_t)v;
        }
    }
#pragma unroll
    for (int rt = 0; rt < 2; ++rt)
      hA[rt][ks] = *(const bf16x8*)&t_s[wid][rt * 16 + l15][quad * 8];
  }

  // ========= Phase B1: hidden = st @ wb1 + bb1   groups 8..9 (FULL unroll) ===
  floatx4 hid[2][4];
#pragma unroll
  for (int gg = 0; gg < 2; ++gg) {
    LD(B1, 8 + gg, 1);
    {
      float bias = bb1[(2 * gg) * 16 + l15];
      floatx4 acc[2];
      GEMM(sA, B0, acc);
      hid[0][2 * gg] = acc[0] + bias;
      hid[1][2 * gg] = acc[1] + bias;
    }
    LD(B0, (gg < 1) ? 9 : 10, 0);
    {
      float bias = bb1[(2 * gg + 1) * 16 + l15];
      floatx4 acc[2];
      GEMM(sA, B1, acc);
      hid[0][2 * gg + 1] = acc[0] + bias;
      hid[1][2 * gg + 1] = acc[1] + bias;
    }
  }

  // ==== Phase B2: W1 = |H1 @ w1b + b1b|; hidden += q.*W1   groups 10..25 =====
  // outer a runtime (code size); 4 tiles/iter keeps buffer parity static.
#pragma unroll 1
  for (int a = 0; a < 8; ++a) {
    float qv[2][4];
#pragma unroll
    for (int rt = 0; rt < 2; ++rt)
#pragma unroll
      for (int i = 0; i < 4; ++i)
        qv[rt][i] = q_s[wid][(rt * 16 + quad * 4 + i) * 8 + a];

    // tile (10+2a, 0) in B0
    LD(B1, 10 + 2 * a, 1);
    {
      float bias = b1b[(4 * a + 0) * 16 + l15];
      floatx4 acc[2];
      GEMM(hA, B0, acc);
#pragma unroll
      for (int rt = 0; rt < 2; ++rt)
#pragma unroll
        for (int i = 0; i < 4; ++i)
          hid[rt][0][i] += qv[rt][i] * fabsf(acc[rt][i] + bias);
    }
    LD(B0, 11 + 2 * a, 0);
    {
      float bias = b1b[(4 * a + 1) * 16 + l15];
      floatx4 acc[2];
      GEMM(hA, B1, acc);
#pragma unroll
      for (int rt = 0; rt < 2; ++rt)
#pragma unroll
        for (int i = 0; i < 4; ++i)
          hid[rt][1][i] += qv[rt][i] * fabsf(acc[rt][i] + bias);
    }
    LD(B1, 11 + 2 * a, 1);
    {
      float bias = b1b[(4 * a + 2) * 16 + l15];
      floatx4 acc[2];
      GEMM(hA, B0, acc);
#pragma unroll
      for (int rt = 0; rt < 2; ++rt)
#pragma unroll
        for (int i = 0; i < 4; ++i)
          hid[rt][2][i] += qv[rt][i] * fabsf(acc[rt][i] + bias);
    }
    LD(B0, (a < 7) ? 12 + 2 * a : 26, 0);
    {
      float bias = b1b[(4 * a + 3) * 16 + l15];
      floatx4 acc[2];
      GEMM(hA, B1, acc);
#pragma unroll
      for (int rt = 0; rt < 2; ++rt)
#pragma unroll
        for (int i = 0; i < 4; ++i)
          hid[rt][3][i] += qv[rt][i] * fabsf(acc[rt][i] + bias);
    }
  }
  // relu
#pragma unroll
  for (int rt = 0; rt < 2; ++rt)
#pragma unroll
    for (int et = 0; et < 4; ++et)
#pragma unroll
      for (int i = 0; i < 4; ++i) hid[rt][et][i] = fmaxf(hid[rt][et][i], 0.f);

  // ========= Phase C: H2 = elu(st @ w2a + b2a)  groups 26..33 (FULL unroll) ==
#pragma unroll
  for (int ks = 0; ks < 8; ++ks) {
    LD(B1, 26 + ks, 1);
    {
      float bias = b2a[(2 * ks) * 16 + l15];
      floatx4 acc[2];
      GEMM(sA, B0, acc);
#pragma unroll
      for (int rt = 0; rt < 2; ++rt)
#pragma unroll
        for (int i = 0; i < 4; ++i) {
          float v = acc[rt][i] + bias;
          v = v > 0.f ? v : (__expf(v) - 1.f);
          t_s[wid][rt * 16 + quad * 4 + i][l15] = (bf16_t)v;
        }
    }
    LD(B0, (ks < 7) ? 27 + ks : 34, 0);
    {
      float bias = b2a[(2 * ks + 1) * 16 + l15];
      floatx4 acc[2];
      GEMM(sA, B1, acc);
#pragma unroll
      for (int rt = 0; rt < 2; ++rt)
#pragma unroll
        for (int i = 0; i < 4; ++i) {
          float v = acc[rt][i] + bias;
          v = v > 0.f ? v : (__expf(v) - 1.f);
          t_s[wid][rt * 16 + quad * 4 + i][16 + l15] = (bf16_t)v;
        }
    }
#pragma unroll
    for (int rt = 0; rt < 2; ++rt)
      hA[rt][ks] = *(const bf16x8*)&t_s[wid][rt * 16 + l15][quad * 8];
  }

  // ==== Phase D: W2 = |H2 @ w2b + b2b|; p += hidden*W2   groups 34..35 ======
  float p[2][4] = {{0.f, 0.f, 0.f, 0.f}, {0.f, 0.f, 0.f, 0.f}};
#pragma unroll
  for (int gg = 0; gg < 2; ++gg) {
    LD(B1, 34 + gg, 1);
    {
      float bias = b2b[(2 * gg) * 16 + l15];
      floatx4 acc[2];
      GEMM(hA, B0, acc);
#pragma unroll
      for (int rt = 0; rt < 2; ++rt)
#pragma unroll
        for (int i = 0; i < 4; ++i)
          p[rt][i] += hid[rt][2 * gg][i] * fabsf(acc[rt][i] + bias);
    }
    LD(B0, (gg < 1) ? 35 : 36, 0);
    {
      float bias = b2b[(2 * gg + 1) * 16 + l15];
      floatx4 acc[2];
      GEMM(hA, B1, acc);
#pragma unroll
      for (int rt = 0; rt < 2; ++rt)
#pragma unroll
        for (int i = 0; i < 4; ++i)
          p[rt][i] += hid[rt][2 * gg + 1][i] * fabsf(acc[rt][i] + bias);
    }
  }

  // == Phase E: HB = elu(st @ wb2a + bb2a); p += HB*wb2b   groups 36..43 =====
#pragma unroll 1
  for (int gg = 0; gg < 8; ++gg) {
    LD(B1, 36 + gg, 1);
    {
      float bias = bb2a[(2 * gg) * 16 + l15];
      float wv   = wb2b[(2 * gg) * 16 + l15];
      floatx4 acc[2];
      GEMM(sA, B0, acc);
#pragma unroll
      for (int rt = 0; rt < 2; ++rt)
#pragma unroll
        for (int i = 0; i < 4; ++i) {
          float v = acc[rt][i] + bias;
          v = v > 0.f ? v : (__expf(v) - 1.f);
          p[rt][i] += v * wv;
        }
    }
    LD(B0, (gg < 7) ? 37 + gg : 43, 0);   // last iter: harmless dummy reload
    {
      float bias = bb2a[(2 * gg + 1) * 16 + l15];
      float wv   = wb2b[(2 * gg + 1) * 16 + l15];
      floatx4 acc[2];
      GEMM(sA, B1, acc);
#pragma unroll
      for (int rt = 0; rt < 2; ++rt)
#pragma unroll
        for (int i = 0; i < 4; ++i) {
          float v = acc[rt][i] + bias;
          v = v > 0.f ? v : (__expf(v) - 1.f);
          p[rt][i] += v * wv;
        }
    }
  }

  // ======= Reduce over 16 column lanes (same row), store joint output ========
  float bb2 = bb2b[0];
#pragma unroll
  for (int rt = 0; rt < 2; ++rt)
#pragma unroll
    for (int i = 0; i < 4; ++i) {
      float v = p[rt][i];
      v += __shfl_xor(v, 1);
      v += __shfl_xor(v, 2);
      v += __shfl_xor(v, 4);
      v += __shfl_xor(v, 8);
      if (l15 == 0) out[m0 + rt * 16 + quad * 4 + i] = v + bb2;
    }
}

// ---------------------------------------------------------------------------
extern "C" void kernel_launch(void* const* d_in, const int* in_sizes, int n_in,
                              void* d_out, int out_size, void* d_ws, size_t ws_size,
                              hipStream_t stream) {
  const float* q    = (const float*)d_in[0];
  const float* st   = (const float*)d_in[1];
  const float* w1a  = (const float*)d_in[2];
  const float* b1a  = (const float*)d_in[3];
  const float* w1b  = (const float*)d_in[4];
  const float* b1b  = (const float*)d_in[5];
  const float* w2a  = (const float*)d_in[6];
  const float* b2a  = (const float*)d_in[7];
  const float* w2b  = (const float*)d_in[8];
  const float* b2b  = (const float*)d_in[9];
  const float* wb1  = (const float*)d_in[10];
  const float* bb1  = (const float*)d_in[11];
  const float* wb2a = (const float*)d_in[12];
  const float* bb2a = (const float*)d_in[13];
  const float* wb2b = (const float*)d_in[14];
  const float* bb2b = (const float*)d_in[15];
  bf16_t* W = (bf16_t*)d_ws;

  hipLaunchKernelGGL(prep_weights, dim3((WS_ELEMS + 255) / 256), dim3(256), 0, stream,
                     w1a, w1b, w2a, w2b, wb1, wb2a, W);
  hipLaunchKernelGGL(mixing_fused, dim3(NTOT / 128), dim3(256), 0, stream,
                     q, st, W, b1a, b1b, b2a, b2b, bb1, bb2a, wb2b, bb2b, (float*)d_out);
}

// Round 5
// 350.856 us; speedup vs baseline: 1.0442x; 1.0173x over previous
//
#include <hip/hip_runtime.h>
#include <math.h>

typedef __bf16 bf16_t;
typedef bf16_t bf16x8 __attribute__((ext_vector_type(8)));
typedef float  floatx4 __attribute__((ext_vector_type(4)));

#define MFMA16(a, b, c) __builtin_amdgcn_mfma_f32_16x16x32_bf16((a), (b), (c), 0, 0, 0)

// Problem constants
constexpr int NTOT = 256 * 512;   // 131072 samples
constexpr int CDIM = 256;         // K for all GEMMs

// ws: flat stream of 88 weight tiles in USE ORDER; tile = 16 output cols x 256 k
// in MFMA B-fragment order: tile[ks][lane][j] (8 KB). Wave B-load = contiguous 1 KB.
//   tiles  0..15 : w1a   (phase A,  groups  0..7)
//   tiles 16..19 : wb1   (phase B1, groups  8..9)
//   tiles 20..51 : w1b   (phase B2, groups 10..25)
//   tiles 52..67 : w2a   (phase C,  groups 26..33)
//   tiles 68..71 : w2b   (phase D,  groups 34..35)
//   tiles 72..87 : wb2a  (phase E,  groups 36..43)
constexpr int N_TILES  = 88;
constexpr int WS_ELEMS = N_TILES * 4096;

// ---------------------------------------------------------------------------
__global__ void prep_weights(const float* __restrict__ w1a, const float* __restrict__ w1b,
                             const float* __restrict__ w2a, const float* __restrict__ w2b,
                             const float* __restrict__ wb1, const float* __restrict__ wb2a,
                             bf16_t* __restrict__ ws) {
  int idx = blockIdx.x * 256 + threadIdx.x;
  if (idx >= WS_ELEMS) return;
  int t   = idx >> 12;       // tile
  int rel = idx & 4095;
  const float* src; int dout; int ct;
  if      (t < 16) { src = w1a;  dout = 256; ct = t; }
  else if (t < 20) { src = wb1;  dout = 64;  ct = t - 16; }
  else if (t < 52) { src = w1b;  dout = 512; ct = t - 20; }
  else if (t < 68) { src = w2a;  dout = 256; ct = t - 52; }
  else if (t < 72) { src = w2b;  dout = 64;  ct = t - 68; }
  else             { src = wb2a; dout = 256; ct = t - 72; }
  int j    = rel & 7;
  int lane = (rel >> 3) & 63;
  int ks   = rel >> 9;
  int o = ct * 16 + (lane & 15);
  int k = ks * 32 + (lane >> 4) * 8 + j;
  ws[idx] = (bf16_t)src[(size_t)k * dout + o];
}

// async global->LDS, 16 B per lane; LDS dest = wave-uniform base + lane*16
__device__ __forceinline__ void gload_lds16(const bf16_t* g, bf16_t* l) {
  __builtin_amdgcn_global_load_lds(
      (const __attribute__((address_space(1))) unsigned int*)g,
      (__attribute__((address_space(3))) unsigned int*)l, 16, 0, 0);
}

// ---------------------------------------------------------------------------
// ROUND-0 STRUCTURE + 3-WAVES/SIMD OCCUPANCY (R4 post-mortem).
//
// History: R0 (this structure, cap 256) = 177us champion, occupancy pinned at
// 2 waves/SIMD because actual unified reg allocation ~224 (sA64+hA64+hid32 +
// ~60 transients). R1 proved 4 blocks/CU physically resident (cap 64, but
// 156-reg spill disaster). R3/R4 proved global-streaming loses to LDS staging.
// Untested middle point: cap 170 -> 3 waves/SIMD. Allocator must shave ~50
// TRANSIENT regs (tighter scheduling), not the 160 persistent ones --
// qualitatively different from R1's cap-64 disaster.
//
// Enablers for 3 blocks/CU:
//  - t_s single-buffered [4][32][36] (the [2] dim gave zero temporal
//    separation -- write and read-back used the same index in one iteration;
//    per-wave in-order LDS makes the WAR safe). LDS 55296 -> 46080 B,
//    3 x 46080 = 138 KB <= 160 KB.
//  - __launch_bounds__(256, 3): CUDA-style min-workgroups-per-CU; clang
//    derives waves/EU = 3*4/4 = 3 -> reg cap ~170. (R1 lesson: (512,4)
//    meant 8 waves/EU -> cap 64.)
//  - reg diet: qv hoisted per-a in B2; pj/pb merged into one p accumulator.
//
// Tripwire: WRITE_SIZE > 50 MB means persistent state spilled -> revert.
//
// Schedule per group:  __syncthreads(); stage(g+1); compute(g)
// (the s_waitcnt vmcnt(0) before s_barrier drains stage(g), which had a full
// compute-group in flight -> ~free).
//
// CRITICAL: every register array (sA, hA, hid, p) must be indexed ONLY with
// compile-time constants, else LLVM demotes it to scratch (observed as
// 131-256 MB WRITE_SIZE). Hence full unrolling below.
// ---------------------------------------------------------------------------
__global__ __launch_bounds__(256, 3)
void mixing_fused(const float* __restrict__ q,     // [N,8]
                  const float* __restrict__ st,    // [N,256]
                  const bf16_t* __restrict__ W,    // ws (tile stream)
                  const float* __restrict__ b1a, const float* __restrict__ b1b,
                  const float* __restrict__ b2a, const float* __restrict__ b2b,
                  const float* __restrict__ bb1,
                  const float* __restrict__ bb2a,
                  const float* __restrict__ wb2b, const float* __restrict__ bb2b,
                  float* __restrict__ out) {
  __shared__ __align__(16) bf16_t wbuf[2][8192];  // 2 x 16 KB weight groups
  __shared__ __align__(16) bf16_t t_s[4][32][36]; // per-wave bounce (transpose)
  __shared__ __align__(16) float  q_s[4][256];    // per-wave q staging

  const int tid  = threadIdx.x;
  const int wid  = tid >> 6;      // 0..3
  const int lane = tid & 63;
  const int l15  = lane & 15;
  const int quad = lane >> 4;
  const int m0   = blockIdx.x * 128 + wid * 32;

  // wave-cooperative stage of group g (16 KB) into wbuf[g&1]; 4 KB per wave
  auto stage = [&](int g) {
    const bf16_t* src = W + (size_t)g * 8192 + wid * 2048 + lane * 8;
    bf16_t* dst = &wbuf[g & 1][wid * 2048];
#pragma unroll
    for (int i = 0; i < 4; ++i)
      gload_lds16(src + i * 512, dst + i * 512);
  };

  // ---- wave-local q staging ----
  *(float4*)&q_s[wid][lane * 4] = *(const float4*)(q + (size_t)m0 * 8 + lane * 4);

  // ---- st A-fragments straight from global (coalesced), cvt to bf16 ----
  bf16x8 sA[2][8];
#pragma unroll
  for (int rt = 0; rt < 2; ++rt) {
    const float* rp = st + (size_t)(m0 + rt * 16 + l15) * CDIM;
#pragma unroll
    for (int ks = 0; ks < 8; ++ks) {
      int k0 = ks * 32 + quad * 8;
      float4 f0 = *(const float4*)(rp + k0);
      float4 f1 = *(const float4*)(rp + k0 + 4);
      bf16x8 v;
      v[0] = (bf16_t)f0.x; v[1] = (bf16_t)f0.y; v[2] = (bf16_t)f0.z; v[3] = (bf16_t)f0.w;
      v[4] = (bf16_t)f1.x; v[5] = (bf16_t)f1.y; v[6] = (bf16_t)f1.z; v[7] = (bf16_t)f1.w;
      sA[rt][ks] = v;
    }
  }

  // GEMM: 16-col tile h (0/1) of LDS group buffer `buf`, both row tiles.
  // A indexed only by constant kk (inner loop fully unrolled).
  auto gemmL = [&](int buf, int h, const bf16x8 (&A)[2][8], floatx4 (&acc)[2]) {
    floatx4 z = {0.f, 0.f, 0.f, 0.f};
    acc[0] = z; acc[1] = z;
#pragma unroll
    for (int kk = 0; kk < 8; ++kk) {
      bf16x8 b = *(const bf16x8*)&wbuf[buf][h * 4096 + kk * 512 + lane * 8];
      acc[0] = MFMA16(A[0][kk], b, acc[0]);
      acc[1] = MFMA16(A[1][kk], b, acc[1]);
    }
  };

  stage(0);

  bf16x8 hA[2][8];

  // ========= Phase A: H1 = elu(st @ w1a + b1a)   groups 0..7 (FULL unroll) ===
#pragma unroll
  for (int ks = 0; ks < 8; ++ks) {
    __syncthreads();
    stage(ks + 1);
    const int buf = ks & 1;
#pragma unroll
    for (int h = 0; h < 2; ++h) {
      int ct = 2 * ks + h;
      floatx4 acc[2];
      gemmL(buf, h, sA, acc);
      float bias = b1a[ct * 16 + l15];
#pragma unroll
      for (int rt = 0; rt < 2; ++rt)
#pragma unroll
        for (int i = 0; i < 4; ++i) {
          float v = acc[rt][i] + bias;
          v = v > 0.f ? v : (__expf(v) - 1.f);
          t_s[wid][rt * 16 + quad * 4 + i][h * 16 + l15] = (bf16_t)v;
        }
    }
#pragma unroll
    for (int rt = 0; rt < 2; ++rt)
      hA[rt][ks] = *(const bf16x8*)&t_s[wid][rt * 16 + l15][quad * 8];
  }

  // ========= Phase B1: hidden = st @ wb1 + bb1   groups 8..9 (FULL unroll) ===
  floatx4 hid[2][4];
#pragma unroll
  for (int gg = 0; gg < 2; ++gg) {
    __syncthreads();
    stage(9 + gg);
    const int buf = gg & 1;
#pragma unroll
    for (int h = 0; h < 2; ++h) {
      int et = 2 * gg + h;
      floatx4 acc[2];
      gemmL(buf, h, sA, acc);
      float bias = bb1[et * 16 + l15];
      hid[0][et] = acc[0] + bias;
      hid[1][et] = acc[1] + bias;
    }
  }

  // ==== Phase B2: W1 = |H1 @ w1b + b1b|; hidden += q.*W1   groups 10..25 =====
  // outer a runtime, inner fully unrolled so et (hid index) is constant.
#pragma unroll 1
  for (int a = 0; a < 8; ++a) {
    float qv[2][4];
#pragma unroll
    for (int rt = 0; rt < 2; ++rt)
#pragma unroll
      for (int i = 0; i < 4; ++i)
        qv[rt][i] = q_s[wid][(rt * 16 + quad * 4 + i) * 8 + a];
#pragma unroll
    for (int g2 = 0; g2 < 2; ++g2) {
      const int idx = a * 2 + g2;          // 0..15
      __syncthreads();
      stage(11 + idx);
      const int buf = g2;                  // (10+idx)&1 == g2
#pragma unroll
      for (int h = 0; h < 2; ++h) {
        int ct = a * 4 + g2 * 2 + h;
        const int et = g2 * 2 + h;         // constant
        floatx4 acc[2];
        gemmL(buf, h, hA, acc);
        float bias = b1b[ct * 16 + l15];
#pragma unroll
        for (int rt = 0; rt < 2; ++rt)
#pragma unroll
          for (int i = 0; i < 4; ++i) {
            float w1v = fabsf(acc[rt][i] + bias);
            hid[rt][et][i] += qv[rt][i] * w1v;
          }
      }
    }
  }
  // relu
#pragma unroll
  for (int rt = 0; rt < 2; ++rt)
#pragma unroll
    for (int et = 0; et < 4; ++et)
#pragma unroll
      for (int i = 0; i < 4; ++i) hid[rt][et][i] = fmaxf(hid[rt][et][i], 0.f);

  // ========= Phase C: H2 = elu(st @ w2a + b2a)  groups 26..33 (FULL unroll) ==
#pragma unroll
  for (int ks = 0; ks < 8; ++ks) {
    __syncthreads();
    stage(27 + ks);
    const int buf = ks & 1;
#pragma unroll
    for (int h = 0; h < 2; ++h) {
      int ct = 2 * ks + h;
      floatx4 acc[2];
      gemmL(buf, h, sA, acc);
      float bias = b2a[ct * 16 + l15];
#pragma unroll
      for (int rt = 0; rt < 2; ++rt)
#pragma unroll
        for (int i = 0; i < 4; ++i) {
          float v = acc[rt][i] + bias;
          v = v > 0.f ? v : (__expf(v) - 1.f);
          t_s[wid][rt * 16 + quad * 4 + i][h * 16 + l15] = (bf16_t)v;
        }
    }
#pragma unroll
    for (int rt = 0; rt < 2; ++rt)
      hA[rt][ks] = *(const bf16x8*)&t_s[wid][rt * 16 + l15][quad * 8];
  }

  // ==== Phase D: W2 = |H2 @ w2b + b2b|; p += hidden*W2   groups 34..35 ======
  float p[2][4] = {{0.f, 0.f, 0.f, 0.f}, {0.f, 0.f, 0.f, 0.f}};
#pragma unroll
  for (int gg = 0; gg < 2; ++gg) {
    __syncthreads();
    stage(35 + gg);
    const int buf = gg & 1;
#pragma unroll
    for (int h = 0; h < 2; ++h) {
      int et = 2 * gg + h;
      floatx4 acc[2];
      gemmL(buf, h, hA, acc);
      float bias = b2b[et * 16 + l15];
#pragma unroll
      for (int rt = 0; rt < 2; ++rt)
#pragma unroll
        for (int i = 0; i < 4; ++i) {
          float w2v = fabsf(acc[rt][i] + bias);
          p[rt][i] += hid[rt][et][i] * w2v;
        }
    }
  }

  // == Phase E: HB = elu(st @ wb2a + bb2a); p += HB*wb2b   groups 36..43 =====
#pragma unroll 1
  for (int gg = 0; gg < 8; ++gg) {
    __syncthreads();
    if (gg < 7) stage(37 + gg);
    const int buf = gg & 1;
#pragma unroll
    for (int h = 0; h < 2; ++h) {
      int ct = 2 * gg + h;
      floatx4 acc[2];
      gemmL(buf, h, sA, acc);
      float bias = bb2a[ct * 16 + l15];
      float wv   = wb2b[ct * 16 + l15];
#pragma unroll
      for (int rt = 0; rt < 2; ++rt)
#pragma unroll
        for (int i = 0; i < 4; ++i) {
          float v = acc[rt][i] + bias;
          v = v > 0.f ? v : (__expf(v) - 1.f);
          p[rt][i] += v * wv;
        }
    }
  }

  // ======= Reduce over 16 column lanes (same row), store joint output ========
  float bb2 = bb2b[0];
#pragma unroll
  for (int rt = 0; rt < 2; ++rt)
#pragma unroll
    for (int i = 0; i < 4; ++i) {
      float v = p[rt][i];
      v += __shfl_xor(v, 1);
      v += __shfl_xor(v, 2);
      v += __shfl_xor(v, 4);
      v += __shfl_xor(v, 8);
      if (l15 == 0) out[m0 + rt * 16 + quad * 4 + i] = v + bb2;
    }
}

// ---------------------------------------------------------------------------
extern "C" void kernel_launch(void* const* d_in, const int* in_sizes, int n_in,
                              void* d_out, int out_size, void* d_ws, size_t ws_size,
                              hipStream_t stream) {
  const float* q    = (const float*)d_in[0];
  const float* st   = (const float*)d_in[1];
  const float* w1a  = (const float*)d_in[2];
  const float* b1a  = (const float*)d_in[3];
  const float* w1b  = (const float*)d_in[4];
  const float* b1b  = (const float*)d_in[5];
  const float* w2a  = (const float*)d_in[6];
  const float* b2a  = (const float*)d_in[7];
  const float* w2b  = (const float*)d_in[8];
  const float* b2b  = (const float*)d_in[9];
  const float* wb1  = (const float*)d_in[10];
  const float* bb1  = (const float*)d_in[11];
  const float* wb2a = (const float*)d_in[12];
  const float* bb2a = (const float*)d_in[13];
  const float* wb2b = (const float*)d_in[14];
  const float* bb2b = (const float*)d_in[15];
  bf16_t* W = (bf16_t*)d_ws;

  hipLaunchKernelGGL(prep_weights, dim3((WS_ELEMS + 255) / 256), dim3(256), 0, stream,
                     w1a, w1b, w2a, w2b, wb1, wb2a, W);
  hipLaunchKernelGGL(mixing_fused, dim3(NTOT / 128), dim3(256), 0, stream,
                     q, st, W, b1a, b1b, b2a, b2b, bb1, bb2a, wb2b, bb2b, (float*)d_out);
}

// Round 6
// 320.345 us; speedup vs baseline: 1.1436x; 1.0952x over previous
//
#include <hip/hip_runtime.h>
#include <math.h>

typedef __bf16 bf16_t;
typedef bf16_t bf16x8 __attribute__((ext_vector_type(8)));
typedef float  floatx4 __attribute__((ext_vector_type(4)));

#define MFMA16(a, b, c) __builtin_amdgcn_mfma_f32_16x16x32_bf16((a), (b), (c), 0, 0, 0)

// Problem constants
constexpr int NTOT = 256 * 512;   // 131072 samples
constexpr int CDIM = 256;         // K for all GEMMs

// ws: flat stream of 88 weight tiles in USE ORDER; tile = 16 output cols x 256 k
// in MFMA B-fragment order: tile[ks][lane][j] (8 KB). Wave B-load = contiguous 1 KB.
//   tiles  0..15 : w1a   (phase A,  groups  0..7)
//   tiles 16..19 : wb1   (phase B1, groups  8..9)
//   tiles 20..51 : w1b   (phase B2, groups 10..25)
//   tiles 52..67 : w2a   (phase C,  groups 26..33)
//   tiles 68..71 : w2b   (phase D,  groups 34..35)
//   tiles 72..87 : wb2a  (phase E,  groups 36..43)
constexpr int N_TILES  = 88;
constexpr int WS_ELEMS = N_TILES * 4096;

// ---------------------------------------------------------------------------
__global__ void prep_weights(const float* __restrict__ w1a, const float* __restrict__ w1b,
                             const float* __restrict__ w2a, const float* __restrict__ w2b,
                             const float* __restrict__ wb1, const float* __restrict__ wb2a,
                             bf16_t* __restrict__ ws) {
  int idx = blockIdx.x * 256 + threadIdx.x;
  if (idx >= WS_ELEMS) return;
  int t   = idx >> 12;       // tile
  int rel = idx & 4095;
  const float* src; int dout; int ct;
  if      (t < 16) { src = w1a;  dout = 256; ct = t; }
  else if (t < 20) { src = wb1;  dout = 64;  ct = t - 16; }
  else if (t < 52) { src = w1b;  dout = 512; ct = t - 20; }
  else if (t < 68) { src = w2a;  dout = 256; ct = t - 52; }
  else if (t < 72) { src = w2b;  dout = 64;  ct = t - 68; }
  else             { src = wb2a; dout = 256; ct = t - 72; }
  int j    = rel & 7;
  int lane = (rel >> 3) & 63;
  int ks   = rel >> 9;
  int o = ct * 16 + (lane & 15);
  int k = ks * 32 + (lane >> 4) * 8 + j;
  ws[idx] = (bf16_t)src[(size_t)k * dout + o];
}

// async global->LDS, 16 B per lane; LDS dest = wave-uniform base + lane*16
__device__ __forceinline__ void gload_lds16(const bf16_t* g, bf16_t* l) {
  __builtin_amdgcn_global_load_lds(
      (const __attribute__((address_space(1))) unsigned int*)g,
      (__attribute__((address_space(3))) unsigned int*)l, 16, 0, 0);
}

// ---------------------------------------------------------------------------
// 16-ROWS-PER-WAVE / 4-WAVES-PER-SIMD VERSION (R5 post-mortem).
//
// Session ledger: the R0 structure (32 rows/wave) carries 160 persistent regs
// (sA64+hA64+hid32) + ~60 transients = ~220 unified -> hard 2 waves/SIMD.
// Every cap trick failed: cap64 (R1) and cap170 (R5) spilled (WRITE_SIZE 200/
// 76 MB), streaming + SW-pipelining (R3/R4) lost to LDS staging. Conclusion:
// shrink the STATE, not the cap. Dropping the rt=2 row-tile dimension halves
// all persistent arrays: sA32+hA32+hid16 = 80 persistent, ~115 total, which
// FITS a cap-128 budget (unlike R1/R5 where demand > cap => spill).
//
// Geometry: 16 rows/wave, block = 4 waves = 64 rows, grid = 2048.
// __launch_bounds__(256,4): waves/EU = 4 blocks * 4 waves / 4 SIMD = 4
// -> reg cap 128, 4 blocks/CU resident (exactly 2 passes, no tail).
// LDS/block = wbuf 32K + t_s[4][16][36] 4.5K + q_s[4][128] 2K = 39,424 B;
// 4 x 39,424 = 157.7 KB <= 160 KB. Chip-wide MFMA count unchanged (each
// MFMA covers 16 rows); per-tile epilogue halves; 4 independent blocks/CU
// de-correlate the per-block barriers that 2 lockstep blocks couldn't hide.
//
// Tripwire: WRITE_SIZE > 50 MB = spill => fall back to (256,3).
//
// Schedule per group:  __syncthreads(); stage(g+1); compute(g)
// (the s_waitcnt vmcnt(0) before s_barrier drains stage(g), which had a full
// compute-group in flight -> ~free).
//
// CRITICAL: every register array (sA, hA, hid, p) must be indexed ONLY with
// compile-time constants, else LLVM demotes it to scratch (observed as
// 131-256 MB WRITE_SIZE). Hence full unrolling below.
// ---------------------------------------------------------------------------
__global__ __launch_bounds__(256, 4)
void mixing_fused(const float* __restrict__ q,     // [N,8]
                  const float* __restrict__ st,    // [N,256]
                  const bf16_t* __restrict__ W,    // ws (tile stream)
                  const float* __restrict__ b1a, const float* __restrict__ b1b,
                  const float* __restrict__ b2a, const float* __restrict__ b2b,
                  const float* __restrict__ bb1,
                  const float* __restrict__ bb2a,
                  const float* __restrict__ wb2b, const float* __restrict__ bb2b,
                  float* __restrict__ out) {
  __shared__ __align__(16) bf16_t wbuf[2][8192];  // 2 x 16 KB weight groups
  __shared__ __align__(16) bf16_t t_s[4][16][36]; // per-wave bounce (transpose)
  __shared__ __align__(16) float  q_s[4][128];    // per-wave q staging

  const int tid  = threadIdx.x;
  const int wid  = tid >> 6;      // 0..3
  const int lane = tid & 63;
  const int l15  = lane & 15;
  const int quad = lane >> 4;
  const int m0   = blockIdx.x * 64 + wid * 16;

  // wave-cooperative stage of group g (16 KB) into wbuf[g&1]; 4 KB per wave
  auto stage = [&](int g) {
    const bf16_t* src = W + (size_t)g * 8192 + wid * 2048 + lane * 8;
    bf16_t* dst = &wbuf[g & 1][wid * 2048];
#pragma unroll
    for (int i = 0; i < 4; ++i)
      gload_lds16(src + i * 512, dst + i * 512);
  };

  // ---- wave-local q staging (16 rows x 8 = 128 floats) ----
  *(float2*)&q_s[wid][lane * 2] = *(const float2*)(q + (size_t)m0 * 8 + lane * 2);

  // ---- st A-fragments straight from global (coalesced), cvt to bf16 ----
  bf16x8 sA[8];
  {
    const float* rp = st + (size_t)(m0 + l15) * CDIM;
#pragma unroll
    for (int ks = 0; ks < 8; ++ks) {
      int k0 = ks * 32 + quad * 8;
      float4 f0 = *(const float4*)(rp + k0);
      float4 f1 = *(const float4*)(rp + k0 + 4);
      bf16x8 v;
      v[0] = (bf16_t)f0.x; v[1] = (bf16_t)f0.y; v[2] = (bf16_t)f0.z; v[3] = (bf16_t)f0.w;
      v[4] = (bf16_t)f1.x; v[5] = (bf16_t)f1.y; v[6] = (bf16_t)f1.z; v[7] = (bf16_t)f1.w;
      sA[ks] = v;
    }
  }

  // GEMM: 16-col tile h (0/1) of LDS group buffer `buf`.
  // A indexed only by constant kk (inner loop fully unrolled).
  auto gemmL = [&](int buf, int h, const bf16x8 (&A)[8], floatx4& acc) {
    floatx4 z = {0.f, 0.f, 0.f, 0.f};
    acc = z;
#pragma unroll
    for (int kk = 0; kk < 8; ++kk) {
      bf16x8 b = *(const bf16x8*)&wbuf[buf][h * 4096 + kk * 512 + lane * 8];
      acc = MFMA16(A[kk], b, acc);
    }
  };

  stage(0);

  bf16x8 hA[8];

  // ========= Phase A: H1 = elu(st @ w1a + b1a)   groups 0..7 (FULL unroll) ===
#pragma unroll
  for (int ks = 0; ks < 8; ++ks) {
    __syncthreads();
    stage(ks + 1);
    const int buf = ks & 1;
#pragma unroll
    for (int h = 0; h < 2; ++h) {
      int ct = 2 * ks + h;
      floatx4 acc;
      gemmL(buf, h, sA, acc);
      float bias = b1a[ct * 16 + l15];
#pragma unroll
      for (int i = 0; i < 4; ++i) {
        float v = acc[i] + bias;
        v = v > 0.f ? v : (__expf(v) - 1.f);
        t_s[wid][quad * 4 + i][h * 16 + l15] = (bf16_t)v;
      }
    }
    hA[ks] = *(const bf16x8*)&t_s[wid][l15][quad * 8];
  }

  // ========= Phase B1: hidden = st @ wb1 + bb1   groups 8..9 (FULL unroll) ===
  floatx4 hid[4];
#pragma unroll
  for (int gg = 0; gg < 2; ++gg) {
    __syncthreads();
    stage(9 + gg);
    const int buf = gg & 1;
#pragma unroll
    for (int h = 0; h < 2; ++h) {
      int et = 2 * gg + h;
      floatx4 acc;
      gemmL(buf, h, sA, acc);
      float bias = bb1[et * 16 + l15];
      hid[et] = acc + bias;
    }
  }

  // ==== Phase B2: W1 = |H1 @ w1b + b1b|; hidden += q.*W1   groups 10..25 =====
  // outer a runtime, inner fully unrolled so et (hid index) is constant.
#pragma unroll 1
  for (int a = 0; a < 8; ++a) {
    float qv[4];
#pragma unroll
    for (int i = 0; i < 4; ++i)
      qv[i] = q_s[wid][(quad * 4 + i) * 8 + a];
#pragma unroll
    for (int g2 = 0; g2 < 2; ++g2) {
      const int idx = a * 2 + g2;          // 0..15
      __syncthreads();
      stage(11 + idx);
      const int buf = g2;                  // (10+idx)&1 == g2
#pragma unroll
      for (int h = 0; h < 2; ++h) {
        int ct = a * 4 + g2 * 2 + h;
        const int et = g2 * 2 + h;         // constant
        floatx4 acc;
        gemmL(buf, h, hA, acc);
        float bias = b1b[ct * 16 + l15];
#pragma unroll
        for (int i = 0; i < 4; ++i) {
          float w1v = fabsf(acc[i] + bias);
          hid[et][i] += qv[i] * w1v;
        }
      }
    }
  }
  // relu
#pragma unroll
  for (int et = 0; et < 4; ++et)
#pragma unroll
    for (int i = 0; i < 4; ++i) hid[et][i] = fmaxf(hid[et][i], 0.f);

  // ========= Phase C: H2 = elu(st @ w2a + b2a)  groups 26..33 (FULL unroll) ==
#pragma unroll
  for (int ks = 0; ks < 8; ++ks) {
    __syncthreads();
    stage(27 + ks);
    const int buf = ks & 1;
#pragma unroll
    for (int h = 0; h < 2; ++h) {
      int ct = 2 * ks + h;
      floatx4 acc;
      gemmL(buf, h, sA, acc);
      float bias = b2a[ct * 16 + l15];
#pragma unroll
      for (int i = 0; i < 4; ++i) {
        float v = acc[i] + bias;
        v = v > 0.f ? v : (__expf(v) - 1.f);
        t_s[wid][quad * 4 + i][h * 16 + l15] = (bf16_t)v;
      }
    }
    hA[ks] = *(const bf16x8*)&t_s[wid][l15][quad * 8];
  }

  // ==== Phase D: W2 = |H2 @ w2b + b2b|; p += hidden*W2   groups 34..35 ======
  float p[4] = {0.f, 0.f, 0.f, 0.f};
#pragma unroll
  for (int gg = 0; gg < 2; ++gg) {
    __syncthreads();
    stage(35 + gg);
    const int buf = gg & 1;
#pragma unroll
    for (int h = 0; h < 2; ++h) {
      int et = 2 * gg + h;
      floatx4 acc;
      gemmL(buf, h, hA, acc);
      float bias = b2b[et * 16 + l15];
#pragma unroll
      for (int i = 0; i < 4; ++i) {
        float w2v = fabsf(acc[i] + bias);
        p[i] += hid[et][i] * w2v;
      }
    }
  }

  // == Phase E: HB = elu(st @ wb2a + bb2a); p += HB*wb2b   groups 36..43 =====
#pragma unroll 1
  for (int gg = 0; gg < 8; ++gg) {
    __syncthreads();
    if (gg < 7) stage(37 + gg);
    const int buf = gg & 1;
#pragma unroll
    for (int h = 0; h < 2; ++h) {
      int ct = 2 * gg + h;
      floatx4 acc;
      gemmL(buf, h, sA, acc);
      float bias = bb2a[ct * 16 + l15];
      float wv   = wb2b[ct * 16 + l15];
#pragma unroll
      for (int i = 0; i < 4; ++i) {
        float v = acc[i] + bias;
        v = v > 0.f ? v : (__expf(v) - 1.f);
        p[i] += v * wv;
      }
    }
  }

  // ======= Reduce over 16 column lanes (same row), store joint output ========
  float bb2 = bb2b[0];
#pragma unroll
  for (int i = 0; i < 4; ++i) {
    float v = p[i];
    v += __shfl_xor(v, 1);
    v += __shfl_xor(v, 2);
    v += __shfl_xor(v, 4);
    v += __shfl_xor(v, 8);
    if (l15 == 0) out[m0 + quad * 4 + i] = v + bb2;
  }
}

// ---------------------------------------------------------------------------
extern "C" void kernel_launch(void* const* d_in, const int* in_sizes, int n_in,
                              void* d_out, int out_size, void* d_ws, size_t ws_size,
                              hipStream_t stream) {
  const float* q    = (const float*)d_in[0];
  const float* st   = (const float*)d_in[1];
  const float* w1a  = (const float*)d_in[2];
  const float* b1a  = (const float*)d_in[3];
  const float* w1b  = (const float*)d_in[4];
  const float* b1b  = (const float*)d_in[5];
  const float* w2a  = (const float*)d_in[6];
  const float* b2a  = (const float*)d_in[7];
  const float* w2b  = (const float*)d_in[8];
  const float* b2b  = (const float*)d_in[9];
  const float* wb1  = (const float*)d_in[10];
  const float* bb1  = (const float*)d_in[11];
  const float* wb2a = (const float*)d_in[12];
  const float* bb2a = (const float*)d_in[13];
  const float* wb2b = (const float*)d_in[14];
  const float* bb2b = (const float*)d_in[15];
  bf16_t* W = (bf16_t*)d_ws;

  hipLaunchKernelGGL(prep_weights, dim3((WS_ELEMS + 255) / 256), dim3(256), 0, stream,
                     w1a, w1b, w2a, w2b, wb1, wb2a, W);
  hipLaunchKernelGGL(mixing_fused, dim3(NTOT / 64), dim3(256), 0, stream,
                     q, st, W, b1a, b1b, b2a, b2b, bb1, bb2a, wb2b, bb2b, (float*)d_out);
}